// Round 6
// baseline (192.283 us; speedup 1.0000x reference)
//
#include <hip/hip_runtime.h>
#include <stdint.h>

#define KNBR 16

typedef float f32x4 __attribute__((ext_vector_type(4)));
typedef float f32x2 __attribute__((ext_vector_type(2)));
typedef __bf16 bf16x8 __attribute__((ext_vector_type(8)));

union ABFrag { uint4 u; bf16x8 v; };

__device__ __forceinline__ uint32_t bf16_rne(float x) {
    uint32_t u = __float_as_uint(x);
    return (u + 0x7fffu + ((u >> 16) & 1u)) >> 16;
}

// searchsorted(BOUNDARIES=[1,2,4,8,16,32,64,128], d) = clamp(exp + (mant!=0), 0, 8)
__device__ __forceinline__ uint32_t bucket_of(float d) {
    uint32_t u = __float_as_uint(d);
    int e = (int)((u >> 23) & 0xff) - 127;
    int b = e + ((u & 0x7fffffu) != 0 ? 1 : 0);
    return (uint32_t)min(max(b, 0), 8);
}

// ---------- prep (one dispatch): cvt tables + pack W ----------
// blocks [0, 2048): fp32 -> bf16 + fp8 tables, grid-stride over n_dwords (float4 units)
// blocks [2048, 2176): pack Wcat=[W_self;W_nbr] into MFMA B-fragment order (32768 items)
__global__ void k_prep(const float* __restrict__ src, uint32_t* __restrict__ ebf,
                       uint32_t* __restrict__ e8, int n_dwords,
                       const float* __restrict__ Ws, const float* __restrict__ Wn,
                       uint16_t* __restrict__ Bp) {
    if (blockIdx.x < 2048) {
        int i = blockIdx.x * blockDim.x + threadIdx.x;
        int stride = 2048 * blockDim.x;
        for (; i < n_dwords; i += stride) {
            float4 v = ((const float4*)src)[i];
            ebf[2 * i]     = bf16_rne(v.x) | (bf16_rne(v.y) << 16);
            ebf[2 * i + 1] = bf16_rne(v.z) | (bf16_rne(v.w) << 16);
            uint32_t p = 0;
            p = __builtin_amdgcn_cvt_pk_fp8_f32(v.x, v.y, p, false);
            p = __builtin_amdgcn_cvt_pk_fp8_f32(v.z, v.w, p, true);
            e8[i] = p;
        }
    } else {
        int o = (blockIdx.x - 2048) * blockDim.x + threadIdx.x;
        if (o >= 8 * 8 * 64 * 8) return;
        int i = o & 7, lane = (o >> 3) & 63, nt = (o >> 9) & 7, ks = o >> 12;
        int r = ks * 32 + (lane >> 4) * 8 + i;
        int c = nt * 16 + (lane & 15);
        float v = (r < 128) ? Ws[r * 128 + c] : Wn[(r - 128) * 128 + c];
        Bp[o] = (uint16_t)bf16_rne(v);
    }
}

// ---------- gather kernel: no LDS, 2-node pipeline per wave, 34 loads in flight ----------
__global__ __launch_bounds__(256, 5) void k_gather(
    const int* __restrict__ node_ids, const int* __restrict__ nbr_idx,
    const float* __restrict__ nbr_dist,
    const uint32_t* __restrict__ emb_bf, const uint16_t* __restrict__ emb8,
    const float* __restrict__ dist_table, uint32_t* __restrict__ A_ws, int n)
{
    const int lane = threadIdx.x & 63;
    const int w = threadIdx.x >> 6;
    const int wid = blockIdx.x * 4 + w;
    const int nwaves = gridDim.x * 4;

    // per-lane dist-table registers: 9 buckets x float2 (features 2*lane, 2*lane+1)
    float2 dreg[9];
    #pragma unroll
    for (int b = 0; b < 9; ++b)
        dreg[b] = *(const float2*)(dist_table + b * 128 + 2 * lane);

    for (int base = wid * 2; base < n; base += nwaves * 2) {
        const bool two = (base + 1 < n);

        // lanes 0..15 translate node0's neighbors, lanes 16..31 node1's (clamped, unused lanes harmless)
        const int gidx = min(base * 16 + lane, n * 16 - 1);
        const uint32_t idx = (uint32_t)nbr_idx[gidx];
        const float dv = nbr_dist[gidx];
        const uint32_t ea = ((uint32_t)node_ids[idx] & 0xFFFFFFu) | (bucket_of(dv) << 24);
        const uint32_t sidv = (uint32_t)node_ids[min(base + (lane & 1), n - 1)];

        const uint32_t s0 = (uint32_t)__builtin_amdgcn_readlane((int)sidv, 0);
        const uint32_t s1 = (uint32_t)__builtin_amdgcn_readlane((int)sidv, 1);
        const uint32_t h0 = emb_bf[(size_t)s0 * 64 + lane];
        const uint32_t h1 = emb_bf[(size_t)s1 * 64 + lane];

        uint32_t p0[KNBR], p1[KNBR];
        uint64_t c0 = 0, c1 = 0;
        #pragma unroll
        for (int k = 0; k < KNBR; ++k) {
            const uint32_t e0 = (uint32_t)__builtin_amdgcn_readlane((int)ea, k);
            const uint32_t e1 = (uint32_t)__builtin_amdgcn_readlane((int)ea, 16 + k);
            p0[k] = (uint32_t)emb8[(size_t)(e0 & 0xFFFFFFu) * 64 + lane];
            p1[k] = (uint32_t)emb8[(size_t)(e1 & 0xFFFFFFu) * 64 + lane];
            c0 += 1ull << (5 * (e0 >> 24));
            c1 += 1ull << (5 * (e1 >> 24));
        }

        float ax0 = 0.f, ay0 = 0.f, ax1 = 0.f, ay1 = 0.f;
        #pragma unroll
        for (int k = 0; k < KNBR; ++k) {
            f32x2 d0 = __builtin_amdgcn_cvt_pk_f32_fp8(p0[k], false);
            f32x2 d1 = __builtin_amdgcn_cvt_pk_f32_fp8(p1[k], false);
            ax0 += d0.x; ay0 += d0.y;
            ax1 += d1.x; ay1 += d1.y;
        }
        #pragma unroll
        for (int b = 0; b < 9; ++b) {
            const float f0 = (float)(uint32_t)((c0 >> (5 * b)) & 31u);
            const float f1 = (float)(uint32_t)((c1 >> (5 * b)) & 31u);
            ax0 += f0 * dreg[b].x; ay0 += f0 * dreg[b].y;
            ax1 += f1 * dreg[b].x; ay1 += f1 * dreg[b].y;
        }
        ax0 *= 0.0625f; ay0 *= 0.0625f; ax1 *= 0.0625f; ay1 *= 0.0625f;

        // A row = 512B: [h: 64 uints][agg: 64 uints], k-order matches GEMM A-frag reads
        uint32_t* r0 = A_ws + (size_t)base * 128;
        r0[lane] = h0;
        r0[64 + lane] = bf16_rne(ax0) | (bf16_rne(ay0) << 16);
        if (two) {
            uint32_t* r1 = A_ws + (size_t)(base + 1) * 128;
            r1[lane] = h1;
            r1[64 + lane] = bf16_rne(ax1) | (bf16_rne(ay1) << 16);
        }
    }
}

// ---------- GEMM kernel: A_ws [ntiles*16 x 256 bf16] @ Bp -> bias+relu -> out ----------
__global__ __launch_bounds__(256, 4) void k_gemm(
    const uint32_t* __restrict__ A_ws, const uint32_t* __restrict__ Bp,
    const float* __restrict__ bias, float* __restrict__ out, int ntiles)
{
    __shared__ float Fs[4 * 16 * 132];
    __shared__ float bsh[128];
    if (threadIdx.x < 128) bsh[threadIdx.x] = bias[threadIdx.x];
    __syncthreads();

    const int lane = threadIdx.x & 63;
    const int w = threadIdx.x >> 6;
    const int l_hi = lane >> 4;
    const int l_lo = lane & 15;
    float* Fw = Fs + w * (16 * 132);

    for (int tile = blockIdx.x * 4 + w; tile < ntiles; tile += gridDim.x * 4) {
        f32x4 acc[8];
        #pragma unroll
        for (int t = 0; t < 8; ++t) acc[t] = (f32x4){0.f, 0.f, 0.f, 0.f};

        const uint32_t* Arow = A_ws + (size_t)(tile * 16 + l_lo) * 128;
        #pragma unroll
        for (int ks = 0; ks < 8; ++ks) {
            ABFrag a;  // A[row=l_lo][k = ks*32 + l_hi*8 + 0..7]
            a.u = *(const uint4*)(Arow + ks * 16 + l_hi * 4);
            #pragma unroll
            for (int nt = 0; nt < 8; ++nt) {
                ABFrag b;  // packed weights, L1/L2-hot
                b.u = ((const uint4*)Bp)[(ks * 8 + nt) * 64 + lane];
                acc[nt] = __builtin_amdgcn_mfma_f32_16x16x32_bf16(a.v, b.v, acc[nt], 0, 0, 0);
            }
        }

        #pragma unroll
        for (int nt = 0; nt < 8; ++nt) {
            const int col = nt * 16 + l_lo;
            const float bv = bsh[col];
            #pragma unroll
            for (int r = 0; r < 4; ++r) {
                float v = acc[nt][r] + bv;
                Fw[(l_hi * 4 + r) * 132 + col] = v > 0.f ? v : 0.f;
            }
        }
        float* dst = out + (size_t)tile * 2048;
        #pragma unroll
        for (int it = 0; it < 8; ++it) {
            const int f = it * 256 + lane * 4;
            const int r = f >> 7, c = f & 127;
            float4 v = *(const float4*)(Fw + r * 132 + c);
            *(float4*)(dst + f) = v;
        }
    }
}

// ---------- fused fallback (mid-size ws): R5 kernel ----------
#define A_STRIDE 132
__global__ __launch_bounds__(1024, 4) void k_main(
    const int* __restrict__ node_ids, const int* __restrict__ nbr_idx,
    const float* __restrict__ nbr_dist,
    const uint32_t* __restrict__ emb_bf, const uint16_t* __restrict__ emb8,
    const float* __restrict__ dist_table, const float* __restrict__ bias,
    const uint32_t* __restrict__ Bp, float* __restrict__ out, int ntiles)
{
    __shared__ uint32_t As[16 * 16 * A_STRIDE];
    __shared__ float bsh[128];
    if (threadIdx.x < 128) bsh[threadIdx.x] = bias[threadIdx.x];
    __syncthreads();

    const int lane = threadIdx.x & 63;
    const int w = threadIdx.x >> 6;
    const int l_hi = lane >> 4;
    const int l_lo = lane & 15;
    uint32_t* Aw = As + w * (16 * A_STRIDE);
    float* Fw = (float*)(As) + w * (16 * A_STRIDE);

    float2 dreg[9];
    #pragma unroll
    for (int b = 0; b < 9; ++b)
        dreg[b] = *(const float2*)(dist_table + b * 128 + 2 * lane);

    const int wid = blockIdx.x * 16 + w;
    const int nwaves = gridDim.x * 16;

    for (int tile = wid; tile < ntiles; tile += nwaves) {
        int4 nb = *(const int4*)(nbr_idx + (size_t)tile * 256 + lane * 4);
        float4 dd = *(const float4*)(nbr_dist + (size_t)tile * 256 + lane * 4);
        uint32_t ea[4];
        ea[0] = (uint32_t)node_ids[nb.x] | (bucket_of(dd.x) << 24);
        ea[1] = (uint32_t)node_ids[nb.y] | (bucket_of(dd.y) << 24);
        ea[2] = (uint32_t)node_ids[nb.z] | (bucket_of(dd.z) << 24);
        ea[3] = (uint32_t)node_ids[nb.w] | (bucket_of(dd.w) << 24);
        uint32_t selfv = (uint32_t)node_ids[(size_t)tile * 16 + (lane & 15)];

        #pragma unroll
        for (int j = 0; j < 16; ++j) {
            const int sw = (j & 7) << 2;
            const uint32_t sid = (uint32_t)__builtin_amdgcn_readlane((int)selfv, j);
            const uint32_t hp = emb_bf[(size_t)sid * 64 + lane];
            uint64_t cnt = 0;
            uint32_t p[KNBR];
            #pragma unroll
            for (int k = 0; k < KNBR; ++k) {
                const uint32_t ew = (uint32_t)__builtin_amdgcn_readlane((int)ea[k & 3], 4 * j + (k >> 2));
                cnt += 1ull << (5 * (ew >> 24));
                p[k] = (uint32_t)emb8[(size_t)(ew & 0xFFFFFFu) * 64 + lane];
            }
            float ax = 0.f, ay = 0.f;
            #pragma unroll
            for (int k = 0; k < KNBR; ++k) {
                f32x2 d = __builtin_amdgcn_cvt_pk_f32_fp8(p[k], false);
                ax += d.x; ay += d.y;
            }
            #pragma unroll
            for (int b = 0; b < 9; ++b) {
                const float fb = (float)(uint32_t)((cnt >> (5 * b)) & 31u);
                ax += fb * dreg[b].x; ay += fb * dreg[b].y;
            }
            ax *= 0.0625f; ay *= 0.0625f;
            Aw[j * A_STRIDE + (lane ^ sw)] = hp;
            Aw[j * A_STRIDE + 64 + (lane ^ sw)] = bf16_rne(ax) | (bf16_rne(ay) << 16);
        }

        asm volatile("s_waitcnt lgkmcnt(0)" ::: "memory");

        f32x4 acc[8];
        #pragma unroll
        for (int t = 0; t < 8; ++t) acc[t] = (f32x4){0.f, 0.f, 0.f, 0.f};
        #pragma unroll
        for (int ks = 0; ks < 8; ++ks) {
            ABFrag a;
            a.u = *(const uint4*)(Aw + l_lo * A_STRIDE + ((ks * 16 + l_hi * 4) ^ ((l_lo & 7) << 2)));
            #pragma unroll
            for (int nt = 0; nt < 8; ++nt) {
                ABFrag b;
                b.u = ((const uint4*)Bp)[(ks * 8 + nt) * 64 + lane];
                acc[nt] = __builtin_amdgcn_mfma_f32_16x16x32_bf16(a.v, b.v, acc[nt], 0, 0, 0);
            }
        }
        #pragma unroll
        for (int nt = 0; nt < 8; ++nt) {
            const int col = nt * 16 + l_lo;
            const float bv = bsh[col];
            #pragma unroll
            for (int r = 0; r < 4; ++r) {
                float v = acc[nt][r] + bv;
                Fw[(l_hi * 4 + r) * A_STRIDE + col] = v > 0.f ? v : 0.f;
            }
        }
        float* dst = out + (size_t)tile * 2048;
        #pragma unroll
        for (int it = 0; it < 8; ++it) {
            const int f = it * 256 + lane * 4;
            const int r = f >> 7, c = f & 127;
            float4 v = *(const float4*)(Fw + r * 132 + c);
            *(float4*)(dst + f) = v;
        }
    }
}

// ---------- safety fallback (tiny ws / tail nodes) ----------
__global__ void k_naive(const int* __restrict__ node_ids, const int* __restrict__ nbr_idx,
                        const float* __restrict__ nbr_dist, const float* __restrict__ emb,
                        const float* __restrict__ dt, const float* __restrict__ Ws,
                        const float* __restrict__ Wn, const float* __restrict__ bias,
                        float* __restrict__ out, int base) {
    __shared__ float h[128], ag[128];
    const int nd = base + blockIdx.x;
    const int t = threadIdx.x;
    const int nid = node_ids[nd];
    float hv = emb[(size_t)nid * 128 + t];
    float a = 0.f;
    for (int k = 0; k < KNBR; ++k) {
        int sn = node_ids[nbr_idx[(size_t)nd * KNBR + k]];
        int bkt = (int)bucket_of(nbr_dist[(size_t)nd * KNBR + k]);
        a += emb[(size_t)sn * 128 + t] + dt[bkt * 128 + t];
    }
    h[t] = hv; ag[t] = a * 0.0625f;
    __syncthreads();
    float s = bias[t];
    for (int d = 0; d < 128; ++d) s += h[d] * Ws[d * 128 + t] + ag[d] * Wn[d * 128 + t];
    out[(size_t)nd * 128 + t] = s > 0.f ? s : 0.f;
}

extern "C" void kernel_launch(void* const* d_in, const int* in_sizes, int n_in,
                              void* d_out, int out_size, void* d_ws, size_t ws_size,
                              hipStream_t stream) {
    const int* node_ids   = (const int*)d_in[0];
    const int* nbr_idx    = (const int*)d_in[1];
    const float* nbr_dist = (const float*)d_in[2];
    const float* emb      = (const float*)d_in[3];
    const float* dist_tab = (const float*)d_in[4];
    const float* Ws       = (const float*)d_in[5];
    const float* Wn       = (const float*)d_in[6];
    const float* bias     = (const float*)d_in[7];
    float* out = (float*)d_out;
    const int n = in_sizes[0];
    const int in_dim = in_sizes[3] / 128;

    const size_t offEbf = 65536;               // after 64KB packed-W
    const size_t offE8  = offEbf + (size_t)in_dim * 256;
    const size_t offA   = offE8 + (size_t)in_dim * 128;
    const size_t needT  = offA;                        // tables only (fused path)
    const size_t needS  = offA + (size_t)n * 512;      // + A_ws (split path)

    if (ws_size < needT) {
        if (n > 0)
            k_naive<<<n, 128, 0, stream>>>(node_ids, nbr_idx, nbr_dist, emb, dist_tab, Ws, Wn, bias, out, 0);
        return;
    }
    uint16_t* Bp   = (uint16_t*)d_ws;
    uint32_t* ebf  = (uint32_t*)((char*)d_ws + offEbf);
    uint32_t* e8   = (uint32_t*)((char*)d_ws + offE8);
    uint32_t* A_ws = (uint32_t*)((char*)d_ws + offA);

    k_prep<<<2176, 256, 0, stream>>>(emb, ebf, e8, in_dim * 32, Ws, Wn, Bp);

    const int ntiles = n >> 4;
    const int rem = n & 15;

    if (ws_size >= needS) {
        if (n > 0)
            k_gather<<<1280, 256, 0, stream>>>(node_ids, nbr_idx, nbr_dist, ebf,
                                               (const uint16_t*)e8, dist_tab, A_ws, n);
        if (ntiles > 0)
            k_gemm<<<640, 256, 0, stream>>>(A_ws, (const uint32_t*)Bp, bias, out, ntiles);
        if (rem > 0)
            k_naive<<<rem, 128, 0, stream>>>(node_ids, nbr_idx, nbr_dist, emb, dist_tab, Ws, Wn, bias, out, ntiles << 4);
    } else {
        if (ntiles > 0)
            k_main<<<256, 1024, 0, stream>>>(node_ids, nbr_idx, nbr_dist, ebf, (const uint16_t*)e8,
                                             dist_tab, bias, (const uint32_t*)Bp, out, ntiles);
        if (rem > 0)
            k_naive<<<rem, 128, 0, stream>>>(node_ids, nbr_idx, nbr_dist, emb, dist_tab, Ws, Wn, bias, out, ntiles << 4);
    }
}

// Round 7
// 151.378 us; speedup vs baseline: 1.2702x; 1.2702x over previous
//
#include <hip/hip_runtime.h>
#include <stdint.h>

#define KNBR 16

typedef float f32x4 __attribute__((ext_vector_type(4)));
typedef float f32x2 __attribute__((ext_vector_type(2)));
typedef __bf16 bf16x8 __attribute__((ext_vector_type(8)));

union ABFrag { uint4 u; bf16x8 v; };

__device__ __forceinline__ uint32_t bf16_rne(float x) {
    uint32_t u = __float_as_uint(x);
    return (u + 0x7fffu + ((u >> 16) & 1u)) >> 16;
}

// searchsorted(BOUNDARIES=[1,2,4,8,16,32,64,128], d) = clamp(exp + (mant!=0), 0, 8)
__device__ __forceinline__ uint32_t bucket_of(float d) {
    uint32_t u = __float_as_uint(d);
    int e = (int)((u >> 23) & 0xff) - 127;
    int b = e + ((u & 0x7fffffu) != 0 ? 1 : 0);
    return (uint32_t)min(max(b, 0), 8);
}

// ---------- prep (one dispatch): cvt tables + pack W ----------
__global__ void k_prep(const float* __restrict__ src, uint32_t* __restrict__ ebf,
                       uint32_t* __restrict__ e8, int n_dwords,
                       const float* __restrict__ Ws, const float* __restrict__ Wn,
                       uint16_t* __restrict__ Bp) {
    if (blockIdx.x < 2048) {
        int i = blockIdx.x * blockDim.x + threadIdx.x;
        int stride = 2048 * blockDim.x;
        for (; i < n_dwords; i += stride) {
            float4 v = ((const float4*)src)[i];
            ebf[2 * i]     = bf16_rne(v.x) | (bf16_rne(v.y) << 16);
            ebf[2 * i + 1] = bf16_rne(v.z) | (bf16_rne(v.w) << 16);
            uint32_t p = 0;
            p = __builtin_amdgcn_cvt_pk_fp8_f32(v.x, v.y, p, false);
            p = __builtin_amdgcn_cvt_pk_fp8_f32(v.z, v.w, p, true);
            e8[i] = p;
        }
    } else {
        int o = (blockIdx.x - 2048) * blockDim.x + threadIdx.x;
        if (o >= 8 * 8 * 64 * 8) return;
        int i = o & 7, lane = (o >> 3) & 63, nt = (o >> 9) & 7, ks = o >> 12;
        int r = ks * 32 + (lane >> 4) * 8 + i;
        int c = nt * 16 + (lane & 15);
        float v = (r < 128) ? Ws[r * 128 + c] : Wn[(r - 128) * 128 + c];
        Bp[o] = (uint16_t)bf16_rne(v);
    }
}

// ---------- fused main: 2-deep pipelined gather + MFMA, A lives only in LDS ----------
#define A_STRIDE 132
__global__ __launch_bounds__(1024, 4) void k_fused(
    const int* __restrict__ node_ids, const int* __restrict__ nbr_idx,
    const float* __restrict__ nbr_dist,
    const uint32_t* __restrict__ emb_bf, const uint16_t* __restrict__ emb8,
    const float* __restrict__ dist_table, const float* __restrict__ bias,
    const uint32_t* __restrict__ Bp, float* __restrict__ out, int ntiles)
{
    __shared__ uint32_t As[16 * 16 * A_STRIDE];   // 135168 B — the only LDS

    const int lane = threadIdx.x & 63;
    const int w = threadIdx.x >> 6;
    const int l_hi = lane >> 4;   // 0..3
    const int l_lo = lane & 15;   // 0..15
    uint32_t* Aw = As + w * (16 * A_STRIDE);
    float* Fw = (float*)(As) + w * (16 * A_STRIDE);

    // dist table in regs: 9 buckets x float2 (features 2*lane, 2*lane+1)
    float2 dreg[9];
    #pragma unroll
    for (int b = 0; b < 9; ++b)
        dreg[b] = *(const float2*)(dist_table + b * 128 + 2 * lane);
    // bias in regs: epilogue col for nt is nt*16 + l_lo
    float breg[8];
    #pragma unroll
    for (int nt = 0; nt < 8; ++nt) breg[nt] = bias[nt * 16 + l_lo];

    const int wid = blockIdx.x * 16 + w;
    const int nwaves = gridDim.x * 16;

    int tile = wid;
    int4 nb; float4 dd; uint32_t selfv = 0;
    if (tile < ntiles) {
        nb = *(const int4*)(nbr_idx + (size_t)tile * 256 + lane * 4);
        dd = *(const float4*)(nbr_dist + (size_t)tile * 256 + lane * 4);
        selfv = (uint32_t)node_ids[(size_t)tile * 16 + (lane & 15)];
    }

    for (; tile < ntiles; tile += nwaves) {
        // ---- phase A: translate this tile's 256 neighbor ids (4 per lane) ----
        uint32_t ea[4];
        ea[0] = ((uint32_t)node_ids[nb.x] & 0xFFFFFFu) | (bucket_of(dd.x) << 24);
        ea[1] = ((uint32_t)node_ids[nb.y] & 0xFFFFFFu) | (bucket_of(dd.y) << 24);
        ea[2] = ((uint32_t)node_ids[nb.z] & 0xFFFFFFu) | (bucket_of(dd.z) << 24);
        ea[3] = ((uint32_t)node_ids[nb.w] & 0xFFFFFFu) | (bucket_of(dd.w) << 24);

        // ---- phase B: 2-deep software pipeline over the 16 nodes ----
        // node j, neighbor k lives in lane 4*j+(k>>2), component k&3
        uint32_t pA[KNBR], pB[KNBR], hA, hB;
        uint64_t cA, cB;

#define ISSUE(J, P, H, C) do {                                                        \
            const uint32_t sid_ = (uint32_t)__builtin_amdgcn_readlane((int)selfv, (J)); \
            (H) = emb_bf[(size_t)sid_ * 64 + lane];                                     \
            (C) = 0;                                                                    \
            _Pragma("unroll")                                                           \
            for (int k = 0; k < KNBR; ++k) {                                            \
                const uint32_t ew_ = (uint32_t)__builtin_amdgcn_readlane(               \
                    (int)ea[k & 3], 4 * (J) + (k >> 2));                                \
                (C) += 1ull << (5 * (ew_ >> 24));                                       \
                (P)[k] = (uint32_t)emb8[(size_t)(ew_ & 0xFFFFFFu) * 64 + lane];         \
            }                                                                           \
        } while (0)

#define CONSUME(J, P, H, C) do {                                                      \
            float ax = 0.f, ay = 0.f;                                                   \
            _Pragma("unroll")                                                           \
            for (int k = 0; k < KNBR; ++k) {                                            \
                f32x2 d_ = __builtin_amdgcn_cvt_pk_f32_fp8((P)[k], false);              \
                ax += d_.x; ay += d_.y;                                                 \
            }                                                                           \
            _Pragma("unroll")                                                           \
            for (int b = 0; b < 9; ++b) {                                               \
                const float fb_ = (float)(uint32_t)(((C) >> (5 * b)) & 31u);            \
                ax += fb_ * dreg[b].x; ay += fb_ * dreg[b].y;                           \
            }                                                                           \
            ax *= 0.0625f; ay *= 0.0625f;                                               \
            const int sw_ = ((J) & 7) << 2;                                             \
            Aw[(J) * A_STRIDE + (lane ^ sw_)] = (H);                                    \
            Aw[(J) * A_STRIDE + 64 + (lane ^ sw_)] = bf16_rne(ax) | (bf16_rne(ay) << 16); \
        } while (0)

        ISSUE(0, pA, hA, cA);
        #pragma unroll
        for (int jj = 0; jj < 16; jj += 2) {
            ISSUE(jj + 1, pB, hB, cB);
            CONSUME(jj, pA, hA, cA);
            if (jj + 2 < 16) ISSUE(jj + 2, pA, hA, cA);
            CONSUME(jj + 1, pB, hB, cB);
        }
#undef ISSUE
#undef CONSUME

        // ---- prefetch next tile's index data (lands under MFMA) ----
        const int tn = tile + nwaves;
        if (tn < ntiles) {
            nb = *(const int4*)(nbr_idx + (size_t)tn * 256 + lane * 4);
            dd = *(const float4*)(nbr_dist + (size_t)tn * 256 + lane * 4);
            selfv = (uint32_t)node_ids[(size_t)tn * 16 + (lane & 15)];
        }

        asm volatile("s_waitcnt lgkmcnt(0)" ::: "memory");

        // ---- MFMA phase: 16 rows x 128 cols, K=256 ----
        f32x4 acc[8];
        #pragma unroll
        for (int t = 0; t < 8; ++t) acc[t] = (f32x4){0.f, 0.f, 0.f, 0.f};

        #pragma unroll
        for (int ks = 0; ks < 8; ++ks) {
            ABFrag a;  // A[row=l_lo][k = ks*32 + l_hi*8 + 0..7]
            a.u = *(const uint4*)(Aw + l_lo * A_STRIDE + ((ks * 16 + l_hi * 4) ^ ((l_lo & 7) << 2)));
            #pragma unroll
            for (int nt = 0; nt < 8; ++nt) {
                ABFrag b;  // packed weights, L2-hot
                b.u = ((const uint4*)Bp)[(ks * 8 + nt) * 64 + lane];
                acc[nt] = __builtin_amdgcn_mfma_f32_16x16x32_bf16(a.v, b.v, acc[nt], 0, 0, 0);
            }
        }

        // ---- epilogue: bias+relu -> LDS transpose -> coalesced full-line stores ----
        #pragma unroll
        for (int nt = 0; nt < 8; ++nt) {
            const int col = nt * 16 + l_lo;
            #pragma unroll
            for (int r = 0; r < 4; ++r) {
                float v = acc[nt][r] + breg[nt];
                Fw[(l_hi * 4 + r) * A_STRIDE + col] = v > 0.f ? v : 0.f;
            }
        }
        float* dst = out + (size_t)tile * 2048;
        #pragma unroll
        for (int it = 0; it < 8; ++it) {
            const int f = it * 256 + lane * 4;
            const int r = f >> 7, c = f & 127;
            float4 v = *(const float4*)(Fw + r * A_STRIDE + c);
            *(float4*)(dst + f) = v;
        }
    }
}

// ---------- safety fallback (tiny ws / tail nodes) ----------
__global__ void k_naive(const int* __restrict__ node_ids, const int* __restrict__ nbr_idx,
                        const float* __restrict__ nbr_dist, const float* __restrict__ emb,
                        const float* __restrict__ dt, const float* __restrict__ Ws,
                        const float* __restrict__ Wn, const float* __restrict__ bias,
                        float* __restrict__ out, int base) {
    __shared__ float h[128], ag[128];
    const int nd = base + blockIdx.x;
    const int t = threadIdx.x;
    const int nid = node_ids[nd];
    float hv = emb[(size_t)nid * 128 + t];
    float a = 0.f;
    for (int k = 0; k < KNBR; ++k) {
        int sn = node_ids[nbr_idx[(size_t)nd * KNBR + k]];
        int bkt = (int)bucket_of(nbr_dist[(size_t)nd * KNBR + k]);
        a += emb[(size_t)sn * 128 + t] + dt[bkt * 128 + t];
    }
    h[t] = hv; ag[t] = a * 0.0625f;
    __syncthreads();
    float s = bias[t];
    for (int d = 0; d < 128; ++d) s += h[d] * Ws[d * 128 + t] + ag[d] * Wn[d * 128 + t];
    out[(size_t)nd * 128 + t] = s > 0.f ? s : 0.f;
}

extern "C" void kernel_launch(void* const* d_in, const int* in_sizes, int n_in,
                              void* d_out, int out_size, void* d_ws, size_t ws_size,
                              hipStream_t stream) {
    const int* node_ids   = (const int*)d_in[0];
    const int* nbr_idx    = (const int*)d_in[1];
    const float* nbr_dist = (const float*)d_in[2];
    const float* emb      = (const float*)d_in[3];
    const float* dist_tab = (const float*)d_in[4];
    const float* Ws       = (const float*)d_in[5];
    const float* Wn       = (const float*)d_in[6];
    const float* bias     = (const float*)d_in[7];
    float* out = (float*)d_out;
    const int n = in_sizes[0];
    const int in_dim = in_sizes[3] / 128;

    const size_t offEbf = 65536;               // after 64KB packed-W
    const size_t offE8  = offEbf + (size_t)in_dim * 256;
    const size_t needT  = offE8 + (size_t)in_dim * 128;

    if (ws_size < needT) {
        if (n > 0)
            k_naive<<<n, 128, 0, stream>>>(node_ids, nbr_idx, nbr_dist, emb, dist_tab, Ws, Wn, bias, out, 0);
        return;
    }
    uint16_t* Bp   = (uint16_t*)d_ws;
    uint32_t* ebf  = (uint32_t*)((char*)d_ws + offEbf);
    uint32_t* e8   = (uint32_t*)((char*)d_ws + offE8);

    k_prep<<<2176, 256, 0, stream>>>(emb, ebf, e8, in_dim * 32, Ws, Wn, Bp);

    const int ntiles = n >> 4;
    const int rem = n & 15;

    if (ntiles > 0)
        k_fused<<<256, 1024, 0, stream>>>(node_ids, nbr_idx, nbr_dist, ebf, (const uint16_t*)e8,
                                          dist_tab, bias, (const uint32_t*)Bp, out, ntiles);
    if (rem > 0)
        k_naive<<<rem, 128, 0, stream>>>(node_ids, nbr_idx, nbr_dist, emb, dist_tab, Ws, Wn, bias, out, ntiles << 4);
}